// Round 12
// baseline (2807.278 us; speedup 1.0000x reference)
//
#include <hip/hip_runtime.h>
#include <hip/hip_fp16.h>
#include <math.h>

typedef _Float16 h16;
typedef __attribute__((ext_vector_type(4))) _Float16 h16x4;
typedef __attribute__((ext_vector_type(8))) _Float16 h16x8;
typedef __attribute__((ext_vector_type(4))) float f32x4;
typedef __attribute__((ext_vector_type(4))) unsigned u32x4;
typedef unsigned long long u64;

#define T_SEQ 512
#define NB    64
#define NI    512
#define NH    1024
#define N3H   3072

#define TAGM 0x0001000100010001ULL   // f16 mantissa LSBs of the 4 packed h

// Agent-scope (LLC-coherent) helpers. Relaxed per-access coherence only —
// no cache-wide fences (r2), no L2 relay (r8), no drain/tag hops (r10):
// h words are SELF-VALIDATING via 4-bit epoch in the f16 LSBs.
__device__ __forceinline__ u64 cload64(const u64* p) {
  return __hip_atomic_load(p, __ATOMIC_RELAXED, __HIP_MEMORY_SCOPE_AGENT);
}
__device__ __forceinline__ void cstore64(u64* p, u64 v) {
  __hip_atomic_store(p, v, __ATOMIC_RELAXED, __HIP_MEMORY_SCOPE_AGENT);
}
// 16B agent-coherent load (r12): HALVES the coherent transaction count
// vs 8B atomic loads. Hand-managed vmcnt; volatile so issue order is kept.
__device__ __forceinline__ u32x4 cload128(const u64* p) {
  u32x4 v;
  asm volatile("global_load_dwordx4 %0, %1, off sc0 sc1" : "=v"(v) : "v"(p));
  return v;
}
#define VMWAIT(N) do { \
  asm volatile("s_waitcnt vmcnt(" #N ")" ::: "memory"); \
  __builtin_amdgcn_sched_barrier(0); \
} while (0)

union H4 { u64 q; h16x4 v; };
union F16B { u32x4 d; u64 q[2]; h16x8 v; };

__device__ __forceinline__ u64 tagpat(unsigned e) {   // spread 4-bit epoch
  return (u64)(e & 1) | ((u64)((e >> 1) & 1) << 16)
       | ((u64)((e >> 2) & 1) << 32) | ((u64)((e >> 3) & 1) << 48);
}

// h planes: [2 parity][4 bg][4096 u64] raw f16 MFMA-fragment order:
// word 2*(kt*64+l)+q holds h[row=l&15][k = kt*32+(l>>4)*8+q*4 .. +3],
// LSB of each f16 = epoch bit. Epoch = (producing_step>>1)&15.
// A lane's 16B fragment (kt) = the dwordx4 at plane + (kt*64+l)*2.

// ============================================================
// Kernel 0: init h^(0) parity-0 planes (raw f16 frag order, epoch 0).
// ============================================================
__global__ void gru_init_h(const float* __restrict__ hid0,
                           u64* __restrict__ hfrag) {
  int W = blockIdx.x * blockDim.x + threadIdx.x;   // 0..16383 (4 bg x 4096)
  if (W >= 16384) return;
  int bg = W >> 12;
  int w  = W & 4095;
  int kt = w >> 7;
  int lp = (w >> 1) & 63;
  int q  = w & 1;
  int cb = kt * 32 + (lp >> 4) * 8 + q * 4;
  H4 o;
  #pragma unroll
  for (int j = 0; j < 4; ++j) o.v[j] = (h16)hid0[cb + j];  // row-independent
  hfrag[(size_t)bg * 4096 + w] = o.q & ~TAGM;              // epoch tag 0
}

// ============================================================
// Kernel 1: x = inp @ W_in + b  (f16 out, CONSUMER-TRANSPOSED layout)
// x layout: [t][gate][cg][bg][cc*16 + rr]  (512B block per (t,g,cg,bg))
// ============================================================
#define P1_BM 128
#define P1_BK 32

__device__ __forceinline__ int p1swz(int r, int k) {
  return r * P1_BK + ((((k >> 3) ^ (r & 3)) << 3) | (k & 7));
}

__global__ __launch_bounds__(256, 2) void gru_xgemm(
    const float* __restrict__ inp, const float* __restrict__ Win,
    const float* __restrict__ bstk, h16* __restrict__ x) {
  __shared__ h16 sAh[2][P1_BM * P1_BK];
  __shared__ h16 sAl[2][P1_BM * P1_BK];
  __shared__ h16 sBh[2][P1_BM * P1_BK];
  __shared__ h16 sBl[2][P1_BM * P1_BK];

  const int tid = threadIdx.x;
  const int l = tid & 63;
  const int w = tid >> 6;
  const int wm = (w >> 1) * 64, wn = (w & 1) * 64;
  const int mi = blockIdx.x, ni = blockIdx.y;

  const int sr  = tid >> 1;
  const int skh = (tid & 1) * 16;

  const float* aSrcBase = inp + (size_t)(sr & 63) * (T_SEQ * NI)
                              + (size_t)(mi * 2 + (sr >> 6)) * NI + skh;
  const float* bSrcBase = Win + (size_t)skh * N3H + ni * 128 + sr;

  f32x4 acc[4][4] = {};
  float aReg[16];
  float bReg[16];

  auto stage_load = [&](int ks) {
    const float* ap = aSrcBase + ks * P1_BK;
    #pragma unroll
    for (int jg = 0; jg < 4; ++jg) {
      f32x4 v = *(const f32x4*)(ap + jg * 4);
      aReg[jg*4+0] = v[0]; aReg[jg*4+1] = v[1];
      aReg[jg*4+2] = v[2]; aReg[jg*4+3] = v[3];
    }
    const float* bp = bSrcBase + (size_t)ks * P1_BK * N3H;
    #pragma unroll
    for (int j = 0; j < 16; ++j) bReg[j] = bp[(size_t)j * N3H];
  };

  auto stage_write = [&](int buf) {
    #pragma unroll
    for (int jg = 0; jg < 4; ++jg) {
      int idx = p1swz(sr, skh + jg * 4);
      h16x4 hi, lo;
      #pragma unroll
      for (int j = 0; j < 4; ++j) {
        float v = aReg[jg*4+j];
        h16 h = (h16)v; hi[j] = h; lo[j] = (h16)(v - (float)h);
      }
      *(h16x4*)&sAh[buf][idx] = hi;
      *(h16x4*)&sAl[buf][idx] = lo;
      #pragma unroll
      for (int j = 0; j < 4; ++j) {
        float v = bReg[jg*4+j];
        h16 h = (h16)v; hi[j] = h; lo[j] = (h16)(v - (float)h);
      }
      *(h16x4*)&sBh[buf][idx] = hi;
      *(h16x4*)&sBl[buf][idx] = lo;
    }
  };

  auto compute = [&](int buf) {
    const int k0 = (l >> 4) * 8;
    h16x8 bh[4], bl[4];
    #pragma unroll
    for (int nt = 0; nt < 4; ++nt) {
      int idx = p1swz(wn + nt * 16 + (l & 15), k0);
      bh[nt] = *(const h16x8*)&sBh[buf][idx];
      bl[nt] = *(const h16x8*)&sBl[buf][idx];
    }
    #pragma unroll
    for (int mt = 0; mt < 4; ++mt) {
      int idx = p1swz(wm + mt * 16 + (l & 15), k0);
      h16x8 ah = *(const h16x8*)&sAh[buf][idx];
      h16x8 al = *(const h16x8*)&sAl[buf][idx];
      #pragma unroll
      for (int nt = 0; nt < 4; ++nt) {
        acc[mt][nt] = __builtin_amdgcn_mfma_f32_16x16x32_f16(ah, bh[nt], acc[mt][nt], 0, 0, 0);
        acc[mt][nt] = __builtin_amdgcn_mfma_f32_16x16x32_f16(ah, bl[nt], acc[mt][nt], 0, 0, 0);
        acc[mt][nt] = __builtin_amdgcn_mfma_f32_16x16x32_f16(al, bh[nt], acc[mt][nt], 0, 0, 0);
      }
    }
  };

  stage_load(0);
  stage_write(0);
  __syncthreads();
  for (int ks = 0; ks < 16; ++ks) {
    int buf = ks & 1;
    if (ks < 15) stage_load(ks + 1);
    compute(buf);
    if (ks < 15) stage_write(buf ^ 1);
    __syncthreads();
  }

  const int t = mi * 2 + (wm >> 6);
  const int rrb = (l >> 4) * 4;
  #pragma unroll
  for (int nt = 0; nt < 4; ++nt) {
    int colhi = ni * 8 + (wn >> 4) + nt;
    int gg  = colhi >> 6;
    int cgx = colhi & 63;
    float bias = bstk[(colhi << 4) + (l & 15)];
    #pragma unroll
    for (int mt = 0; mt < 4; ++mt) {
      h16x4 v;
      #pragma unroll
      for (int i = 0; i < 4; ++i) v[i] = (h16)(acc[mt][nt][i] + bias);
      size_t idx = ((((size_t)t * 3 + gg) * 64 + cgx) * 4 + mt) * 256
                 + (size_t)(l & 15) * 16 + rrb;
      *(h16x4*)&x[idx] = v;
    }
  }
}

// ============================================================
// Kernel 2: persistent GRU recurrence — single-wave step loop,
// self-validating fragments, 16B sc0+sc1 pulls with counted vmcnt
// pipeline (3-slot chunk rotation). No barriers/drain/tag array.
// ============================================================
__global__ __launch_bounds__(192, 1) void gru_steps(
    const float* __restrict__ Whid,   // [1024][3072] f32
    const h16* __restrict__ x,        // transposed layout, f16
    u64* __restrict__ hfrag,          // [2 par][4 bg][4096] u64 tagged frags
    const float* __restrict__ hid0,   // [1024]
    float* __restrict__ out) {        // [64][1024] f32
  __shared__ h16 U[3 * 32 * 64 * 8];  // 96 KiB fragment-ordered W_hid slice
  __shared__ h16 tq[16 * 20];         // store-transpose staging

  const int tid = threadIdx.x;
  const int l = tid & 63;
  const int g = tid >> 6;
  const int cg = blockIdx.x & 63;
  const int bg = blockIdx.x >> 6;

  // ---- one-time: W_hid slice -> fragment-ordered LDS (3 waves) ----
  {
    const float* base = Whid + (size_t)g * NH + (size_t)cg * 16 + (l & 15);
    for (int kt = 0; kt < 32; ++kt) {
      const float* src = base + (size_t)(kt * 32 + (l >> 4) * 8) * N3H;
      h16x8 v;
      #pragma unroll
      for (int j = 0; j < 8; ++j) v[j] = (h16)src[(size_t)j * N3H];
      *(h16x8*)&U[(size_t)((g * 32 + kt) * 64 + l) * 8] = v;
    }
  }
  __syncthreads();
  if (g != 0) return;    // steps run on wave 0 only

  const int rr0 = (l >> 4) * 4, cc = l & 15;

  float hq[4];
  {
    float h0 = hid0[cg * 16 + cc];
    #pragma unroll
    for (int i = 0; i < 4; ++i) hq[i] = h0;
  }

  const char* xb0 = (const char*)(x + ((((size_t)0 * 64 + cg) * 4 + bg) * 256)
                                    + (size_t)cc * 16 + rr0);
  const char* xb1 = xb0 + 64 * 4 * 256 * 2;
  const char* xb2 = xb1 + 64 * 4 * 256 * 2;
  u64 xq0 = *(const u64*)xb0, xq1 = *(const u64*)xb1, xq2 = *(const u64*)xb2;

  const int dstw = cg * 64 + ((l >> 4) >> 1) * 32 + (l & 15) * 2 + ((l >> 4) & 1);

  VMWAIT(0);   // deterministic vm state entering the step loop

  for (int s = 1; s <= T_SEQ; ++s) {
    const u64* plane = hfrag + ((size_t)((s - 1) & 1) * 4 + bg) * 4096;
    const u64 patc = tagpat((((unsigned)(s - 1)) >> 1) & 15u);

    f32x4 ac0 = {}, ac1 = {}, ac2 = {};
    F16B W0[8], W1[8], W2[8];   // 3 chunk slots (c3 reuses slot 0)

    auto issue = [&](F16B (&W)[8], int c) {
      #pragma unroll
      for (int j = 0; j < 8; ++j)
        W[j].d = cload128(plane + ((size_t)(c * 8 + j) * 64 + l) * 2);
    };
    auto fix = [&](F16B (&W)[8], int c) {     // rare path: re-pull stale frags
      for (int tries = 0; tries < 30000; ++tries) {
        unsigned bad = 0;
        #pragma unroll
        for (int j = 0; j < 8; ++j)
          bad |= ((((W[j].q[0] ^ patc) | (W[j].q[1] ^ patc)) & TAGM) != 0ULL)
                   ? (1u << j) : 0u;
        if (bad == 0) break;
        if (tries > 4) __builtin_amdgcn_s_sleep(1);
        #pragma unroll
        for (int j = 0; j < 8; ++j)
          if (bad & (1u << j))
            W[j].d = cload128(plane + ((size_t)(c * 8 + j) * 64 + l) * 2);
        VMWAIT(0);
      }
    };
    auto mfmac = [&](F16B (&W)[8], int c) {
      #pragma unroll
      for (int j = 0; j < 8; ++j) {
        int kt = c * 8 + j;
        h16x8 b0 = *(const h16x8*)&U[(size_t)((0 * 32 + kt) * 64 + l) * 8];
        h16x8 b1 = *(const h16x8*)&U[(size_t)((1 * 32 + kt) * 64 + l) * 8];
        h16x8 b2 = *(const h16x8*)&U[(size_t)((2 * 32 + kt) * 64 + l) * 8];
        ac0 = __builtin_amdgcn_mfma_f32_16x16x32_f16(W[j].v, b0, ac0, 0, 0, 0);
        ac1 = __builtin_amdgcn_mfma_f32_16x16x32_f16(W[j].v, b1, ac1, 0, 0, 0);
        ac2 = __builtin_amdgcn_mfma_f32_16x16x32_f16(W[j].v, b2, ac2, 0, 0, 0);
      }
    };

    // counted pipeline: stray tail ops (1 store + 3 prefetch) retire first.
    issue(W0, 0);
    issue(W1, 1);
    VMWAIT(8);          // c0 landed (c1's 8 still outstanding)
    fix(W0, 0);
    issue(W2, 2);
    mfmac(W0, 0);       // slot 0 free after this
    issue(W0, 3);       // c3 -> slot 0
    VMWAIT(16);         // c1 landed (c2+c3 = 16 outstanding)
    fix(W1, 1);
    mfmac(W1, 1);
    VMWAIT(8);          // c2 landed (c3 = 8 outstanding)
    fix(W2, 2);
    mfmac(W2, 2);
    VMWAIT(0);          // c3 landed
    fix(W0, 3);
    mfmac(W0, 3);

    // ---- gates fully in-register ----
    H4 xr; xr.q = xq0;
    H4 xu; xu.q = xq1;
    H4 xc; xc.q = xq2;
    #pragma unroll
    for (int i = 0; i < 4; ++i) {
      float r = 1.0f / (1.0f + __expf(-((float)xr.v[i] + ac0[i])));
      float u = 1.0f / (1.0f + __expf(-((float)xu.v[i] + ac1[i])));
      float z = (float)xc.v[i] + r * ac2[i];
      float e = __expf(2.0f * z);
      float c = 1.0f - 2.0f / (e + 1.0f);      // tanh(z)
      float hn = (1.0f - u) * hq[i] + u * c;
      hq[i] = hn;
      tq[(rr0 + i) * 20 + cc] = (h16)hn;
      if (s == T_SEQ) out[(size_t)(bg * 16 + rr0 + i) * NH + cg * 16 + cc] = hn;
    }

    // ---- transpose -> one tagged 8B store; then next-x prefetch ----
    H4 pv; pv.v = *(const h16x4*)&tq[(l & 15) * 20 + (l >> 4) * 4];
    u64 word = (pv.q & ~TAGM) | tagpat(((unsigned)s >> 1) & 15u);
    u64* outp = hfrag + ((size_t)(s & 1) * 4 + bg) * 4096;
    cstore64(outp + dstw, word);

    if (s < T_SEQ) {
      xq0 = *(const u64*)(xb0 + (size_t)s * 393216);
      xq1 = *(const u64*)(xb1 + (size_t)s * 393216);
      xq2 = *(const u64*)(xb2 + (size_t)s * 393216);
    }
  }
}

// ============================================================
extern "C" void kernel_launch(void* const* d_in, const int* in_sizes, int n_in,
                              void* d_out, int out_size, void* d_ws, size_t ws_size,
                              hipStream_t stream) {
  const float* inp  = (const float*)d_in[0];
  const float* Win  = (const float*)d_in[1];
  const float* Whid = (const float*)d_in[2];
  const float* bstk = (const float*)d_in[3];
  const float* hid0 = (const float*)d_in[4];
  float* out = (float*)d_out;

  char* ws = (char*)d_ws;
  const size_t xBytes = (size_t)T_SEQ * NB * N3H * sizeof(h16);   // 201,326,592
  const size_t hBytes = (size_t)2 * 4 * 4096 * sizeof(u64);       //     262,144
  if (ws_size < xBytes + hBytes) return;

  h16* x = (h16*)ws;
  u64* hfrag = (u64*)(ws + xBytes);

  gru_init_h<<<dim3(16384 / 256), dim3(256), 0, stream>>>(hid0, hfrag);

  dim3 g1(32768 / P1_BM, N3H / 128);
  gru_xgemm<<<g1, dim3(256), 0, stream>>>(inp, Win, bstk, x);

  gru_steps<<<dim3(256), dim3(192), 0, stream>>>(Whid, x, hfrag, hid0, out);
}

// Round 13
// 2427.293 us; speedup vs baseline: 1.1565x; 1.1565x over previous
//
#include <hip/hip_runtime.h>
#include <hip/hip_fp16.h>
#include <math.h>

typedef _Float16 h16;
typedef __attribute__((ext_vector_type(4))) _Float16 h16x4;
typedef __attribute__((ext_vector_type(8))) _Float16 h16x8;
typedef __attribute__((ext_vector_type(4))) float f32x4;
typedef __attribute__((ext_vector_type(4))) unsigned u32x4;
typedef unsigned long long u64;

#define T_SEQ 512
#define NB    64
#define NI    512
#define NH    1024
#define N3H   3072

#define TAGM 0x0001000100010001ULL   // f16 mantissa LSBs of the 4 packed h

// Agent-scope (LLC-coherent) helpers. Relaxed per-access coherence only —
// no cache-wide fences (r2), no L2 relay (r8). h words are SELF-VALIDATING
// via 4-bit epoch in the f16 LSBs (r11 protocol, kept bit-identical).
__device__ __forceinline__ void cstore64(u64* p, u64 v) {
  __hip_atomic_store(p, v, __ATOMIC_RELAXED, __HIP_MEMORY_SCOPE_AGENT);
}
__device__ __forceinline__ u32x4 cload128(const u64* p) {
  u32x4 v;
  asm volatile("global_load_dwordx4 %0, %1, off sc0 sc1" : "=v"(v) : "v"(p));
  return v;
}
#define VMWAIT(N) do { \
  asm volatile("s_waitcnt vmcnt(" #N ")" ::: "memory"); \
  __builtin_amdgcn_sched_barrier(0); \
} while (0)

union H4 { u64 q; h16x4 v; };
union F16B { u32x4 d; u64 q[2]; h16x8 v; };

__device__ __forceinline__ u64 tagpat(unsigned e) {   // spread 4-bit epoch
  return (u64)(e & 1) | ((u64)((e >> 1) & 1) << 16)
       | ((u64)((e >> 2) & 1) << 32) | ((u64)((e >> 3) & 1) << 48);
}

// h planes: [2 parity][4 bg][4096 u64] raw f16 MFMA-fragment order:
// word 2*(kt*64+l)+q holds h[row=l&15][k = kt*32+(l>>4)*8+q*4 .. +3],
// LSB of each f16 = epoch bit. Epoch = (producing_step>>1)&15.

// ============================================================
// Kernel 0: init h^(0) parity-0 planes (raw f16 frag order, epoch 0).
// ============================================================
__global__ void gru_init_h(const float* __restrict__ hid0,
                           u64* __restrict__ hfrag) {
  int W = blockIdx.x * blockDim.x + threadIdx.x;   // 0..16383 (4 bg x 4096)
  if (W >= 16384) return;
  int bg = W >> 12;
  int w  = W & 4095;
  int kt = w >> 7;
  int lp = (w >> 1) & 63;
  int q  = w & 1;
  int cb = kt * 32 + (lp >> 4) * 8 + q * 4;
  H4 o;
  #pragma unroll
  for (int j = 0; j < 4; ++j) o.v[j] = (h16)hid0[cb + j];  // row-independent
  hfrag[(size_t)bg * 4096 + w] = o.q & ~TAGM;              // epoch tag 0
}

// ============================================================
// Kernel 1: x = inp @ W_in + b  (f16 out, CONSUMER-TRANSPOSED layout)
// x layout: [t][gate][cg][bg][cc*16 + rr]  (512B block per (t,g,cg,bg))
// ============================================================
#define P1_BM 128
#define P1_BK 32

__device__ __forceinline__ int p1swz(int r, int k) {
  return r * P1_BK + ((((k >> 3) ^ (r & 3)) << 3) | (k & 7));
}

__global__ __launch_bounds__(256, 2) void gru_xgemm(
    const float* __restrict__ inp, const float* __restrict__ Win,
    const float* __restrict__ bstk, h16* __restrict__ x) {
  __shared__ h16 sAh[2][P1_BM * P1_BK];
  __shared__ h16 sAl[2][P1_BM * P1_BK];
  __shared__ h16 sBh[2][P1_BM * P1_BK];
  __shared__ h16 sBl[2][P1_BM * P1_BK];

  const int tid = threadIdx.x;
  const int l = tid & 63;
  const int w = tid >> 6;
  const int wm = (w >> 1) * 64, wn = (w & 1) * 64;
  const int mi = blockIdx.x, ni = blockIdx.y;

  const int sr  = tid >> 1;
  const int skh = (tid & 1) * 16;

  const float* aSrcBase = inp + (size_t)(sr & 63) * (T_SEQ * NI)
                              + (size_t)(mi * 2 + (sr >> 6)) * NI + skh;
  const float* bSrcBase = Win + (size_t)skh * N3H + ni * 128 + sr;

  f32x4 acc[4][4] = {};
  float aReg[16];
  float bReg[16];

  auto stage_load = [&](int ks) {
    const float* ap = aSrcBase + ks * P1_BK;
    #pragma unroll
    for (int jg = 0; jg < 4; ++jg) {
      f32x4 v = *(const f32x4*)(ap + jg * 4);
      aReg[jg*4+0] = v[0]; aReg[jg*4+1] = v[1];
      aReg[jg*4+2] = v[2]; aReg[jg*4+3] = v[3];
    }
    const float* bp = bSrcBase + (size_t)ks * P1_BK * N3H;
    #pragma unroll
    for (int j = 0; j < 16; ++j) bReg[j] = bp[(size_t)j * N3H];
  };

  auto stage_write = [&](int buf) {
    #pragma unroll
    for (int jg = 0; jg < 4; ++jg) {
      int idx = p1swz(sr, skh + jg * 4);
      h16x4 hi, lo;
      #pragma unroll
      for (int j = 0; j < 4; ++j) {
        float v = aReg[jg*4+j];
        h16 h = (h16)v; hi[j] = h; lo[j] = (h16)(v - (float)h);
      }
      *(h16x4*)&sAh[buf][idx] = hi;
      *(h16x4*)&sAl[buf][idx] = lo;
      #pragma unroll
      for (int j = 0; j < 4; ++j) {
        float v = bReg[jg*4+j];
        h16 h = (h16)v; hi[j] = h; lo[j] = (h16)(v - (float)h);
      }
      *(h16x4*)&sBh[buf][idx] = hi;
      *(h16x4*)&sBl[buf][idx] = lo;
    }
  };

  auto compute = [&](int buf) {
    const int k0 = (l >> 4) * 8;
    h16x8 bh[4], bl[4];
    #pragma unroll
    for (int nt = 0; nt < 4; ++nt) {
      int idx = p1swz(wn + nt * 16 + (l & 15), k0);
      bh[nt] = *(const h16x8*)&sBh[buf][idx];
      bl[nt] = *(const h16x8*)&sBl[buf][idx];
    }
    #pragma unroll
    for (int mt = 0; mt < 4; ++mt) {
      int idx = p1swz(wm + mt * 16 + (l & 15), k0);
      h16x8 ah = *(const h16x8*)&sAh[buf][idx];
      h16x8 al = *(const h16x8*)&sAl[buf][idx];
      #pragma unroll
      for (int nt = 0; nt < 4; ++nt) {
        acc[mt][nt] = __builtin_amdgcn_mfma_f32_16x16x32_f16(ah, bh[nt], acc[mt][nt], 0, 0, 0);
        acc[mt][nt] = __builtin_amdgcn_mfma_f32_16x16x32_f16(ah, bl[nt], acc[mt][nt], 0, 0, 0);
        acc[mt][nt] = __builtin_amdgcn_mfma_f32_16x16x32_f16(al, bh[nt], acc[mt][nt], 0, 0, 0);
      }
    }
  };

  stage_load(0);
  stage_write(0);
  __syncthreads();
  for (int ks = 0; ks < 16; ++ks) {
    int buf = ks & 1;
    if (ks < 15) stage_load(ks + 1);
    compute(buf);
    if (ks < 15) stage_write(buf ^ 1);
    __syncthreads();
  }

  const int t = mi * 2 + (wm >> 6);
  const int rrb = (l >> 4) * 4;
  #pragma unroll
  for (int nt = 0; nt < 4; ++nt) {
    int colhi = ni * 8 + (wn >> 4) + nt;
    int gg  = colhi >> 6;
    int cgx = colhi & 63;
    float bias = bstk[(colhi << 4) + (l & 15)];
    #pragma unroll
    for (int mt = 0; mt < 4; ++mt) {
      h16x4 v;
      #pragma unroll
      for (int i = 0; i < 4; ++i) v[i] = (h16)(acc[mt][nt][i] + bias);
      size_t idx = ((((size_t)t * 3 + gg) * 64 + cgx) * 4 + mt) * 256
                 + (size_t)(l & 15) * 16 + rrb;
      *(h16x4*)&x[idx] = v;
    }
  }
}

// ============================================================
// Kernel 2: persistent GRU recurrence — 64 WGs x 4 waves (r13).
// Each WG owns 64 h-cols (4 waves x 16); the 32KB h plane is pulled
// ONCE per WG (4x less coherent traffic than r12) into an LDS parity
// double-buffer; B operands live in VGPRs (r,u + 24/32 of c) with the
// c-gate tail in LDS. Protocol/wire format identical to r12.
// ============================================================
__global__ __launch_bounds__(256, 1) void gru_steps(
    const float* __restrict__ Whid,   // [1024][3072] f32
    const h16* __restrict__ x,        // transposed layout, f16
    u64* __restrict__ hfrag,          // [2 par][4 bg][4096] u64 tagged frags
    const float* __restrict__ hid0,   // [1024]
    float* __restrict__ out) {        // [64][1024] f32
  __shared__ h16 Albuf[2][16384];     // 64 KiB: staged h plane, parity dbuf
  __shared__ h16 Bc2[4 * 8 * 64 * 8]; // 32 KiB: gate-c B frags kt=24..31
  __shared__ h16 tq[4][16 * 20];      // per-wave store-transpose staging

  const int tid = threadIdx.x;
  const int l = tid & 63;
  const int w = tid >> 6;              // wave id 0..3
  const int cg = (blockIdx.x >> 2) * 4 + w;   // this wave's 16-col tile
  const int bg = blockIdx.x & 3;

  // ---- prologue: B fragments -> registers (+ gate-c tail -> LDS) ----
  h16x8 Br[32], Bu[32], Bc[24];
  {
    const float* b0 = Whid + (size_t)cg * 16 + (l & 15);
    #pragma unroll
    for (int kt = 0; kt < 32; ++kt) {
      const float* src = b0 + (size_t)(kt * 32 + (l >> 4) * 8) * N3H;
      h16x8 v;
      #pragma unroll
      for (int j = 0; j < 8; ++j) v[j] = (h16)src[(size_t)j * N3H];
      Br[kt] = v;
    }
    const float* b1 = b0 + NH;
    #pragma unroll
    for (int kt = 0; kt < 32; ++kt) {
      const float* src = b1 + (size_t)(kt * 32 + (l >> 4) * 8) * N3H;
      h16x8 v;
      #pragma unroll
      for (int j = 0; j < 8; ++j) v[j] = (h16)src[(size_t)j * N3H];
      Bu[kt] = v;
    }
    const float* b2 = b0 + 2 * NH;
    #pragma unroll
    for (int kt = 0; kt < 24; ++kt) {
      const float* src = b2 + (size_t)(kt * 32 + (l >> 4) * 8) * N3H;
      h16x8 v;
      #pragma unroll
      for (int j = 0; j < 8; ++j) v[j] = (h16)src[(size_t)j * N3H];
      Bc[kt] = v;
    }
    #pragma unroll
    for (int kt = 24; kt < 32; ++kt) {
      const float* src = b2 + (size_t)(kt * 32 + (l >> 4) * 8) * N3H;
      h16x8 v;
      #pragma unroll
      for (int j = 0; j < 8; ++j) v[j] = (h16)src[(size_t)j * N3H];
      *(h16x8*)&Bc2[(size_t)((w * 8 + (kt - 24)) * 64 + l) * 8] = v;
    }
  }

  const int rr0 = (l >> 4) * 4, cc = l & 15;

  float hq[4];
  {
    float h0 = hid0[cg * 16 + cc];
    #pragma unroll
    for (int i = 0; i < 4; ++i) hq[i] = h0;
  }

  const char* xb0 = (const char*)(x + ((((size_t)0 * 64 + cg) * 4 + bg) * 256)
                                    + (size_t)cc * 16 + rr0);
  const char* xb1 = xb0 + 64 * 4 * 256 * 2;
  const char* xb2 = xb1 + 64 * 4 * 256 * 2;
  u64 xq0 = *(const u64*)xb0, xq1 = *(const u64*)xb1, xq2 = *(const u64*)xb2;

  const int dstw = cg * 64 + ((l >> 4) >> 1) * 32 + (l & 15) * 2 + ((l >> 4) & 1);

  VMWAIT(0);           // deterministic vm state entering the loop
  __syncthreads();

  for (int s = 1; s <= T_SEQ; ++s) {
    const int par = (s - 1) & 1;
    const u64* plane = hfrag + ((size_t)par * 4 + bg) * 4096;
    const u64 patc = tagpat((((unsigned)(s - 1)) >> 1) & 15u);

    // ---- cooperative pull: 8 frags/thread (2 chunks of 4), 2MB/step/chip ----
    F16B W0[4], W1[4];
    #pragma unroll
    for (int j = 0; j < 4; ++j)
      W0[j].d = cload128(plane + (size_t)(j * 256 + tid) * 2);
    #pragma unroll
    for (int j = 0; j < 4; ++j)
      W1[j].d = cload128(plane + (size_t)((4 + j) * 256 + tid) * 2);

    VMWAIT(4);          // strays (<=4: store+3 x-loads) + chunk0 retired
    for (int tries = 0; tries < 30000; ++tries) {
      unsigned bad = 0;
      #pragma unroll
      for (int j = 0; j < 4; ++j)
        bad |= ((((W0[j].q[0] ^ patc) | (W0[j].q[1] ^ patc)) & TAGM) != 0ULL)
                 ? (1u << j) : 0u;
      if (bad == 0) break;
      if (tries > 4) __builtin_amdgcn_s_sleep(1);
      #pragma unroll
      for (int j = 0; j < 4; ++j)
        if (bad & (1u << j))
          W0[j].d = cload128(plane + (size_t)(j * 256 + tid) * 2);
      VMWAIT(0);
    }
    #pragma unroll
    for (int j = 0; j < 4; ++j)
      *(h16x8*)&Albuf[par][(size_t)(j * 256 + tid) * 8] = W0[j].v;

    VMWAIT(0);          // chunk1 retired
    for (int tries = 0; tries < 30000; ++tries) {
      unsigned bad = 0;
      #pragma unroll
      for (int j = 0; j < 4; ++j)
        bad |= ((((W1[j].q[0] ^ patc) | (W1[j].q[1] ^ patc)) & TAGM) != 0ULL)
                 ? (1u << j) : 0u;
      if (bad == 0) break;
      if (tries > 4) __builtin_amdgcn_s_sleep(1);
      #pragma unroll
      for (int j = 0; j < 4; ++j)
        if (bad & (1u << j))
          W1[j].d = cload128(plane + (size_t)((4 + j) * 256 + tid) * 2);
      VMWAIT(0);
    }
    #pragma unroll
    for (int j = 0; j < 4; ++j)
      *(h16x8*)&Albuf[par][(size_t)((4 + j) * 256 + tid) * 8] = W1[j].v;

    __syncthreads();    // plane staged; safe vs parity dbuf (see journal)

    // ---- 96 MFMA per wave: A from LDS (broadcast), B from VGPR/LDS ----
    f32x4 ac0 = {}, ac1 = {}, ac2 = {};
    #pragma unroll
    for (int kt = 0; kt < 32; ++kt) {
      h16x8 a = *(const h16x8*)&Albuf[par][(size_t)(kt * 64 + l) * 8];
      ac0 = __builtin_amdgcn_mfma_f32_16x16x32_f16(a, Br[kt], ac0, 0, 0, 0);
      ac1 = __builtin_amdgcn_mfma_f32_16x16x32_f16(a, Bu[kt], ac1, 0, 0, 0);
      h16x8 bc = (kt < 24)
          ? Bc[kt]
          : *(const h16x8*)&Bc2[(size_t)((w * 8 + (kt - 24)) * 64 + l) * 8];
      ac2 = __builtin_amdgcn_mfma_f32_16x16x32_f16(a, bc, ac2, 0, 0, 0);
    }

    // ---- gates fully in-register (identical numerics to r12) ----
    H4 xr; xr.q = xq0;
    H4 xu; xu.q = xq1;
    H4 xc; xc.q = xq2;
    #pragma unroll
    for (int i = 0; i < 4; ++i) {
      float r = 1.0f / (1.0f + __expf(-((float)xr.v[i] + ac0[i])));
      float u = 1.0f / (1.0f + __expf(-((float)xu.v[i] + ac1[i])));
      float z = (float)xc.v[i] + r * ac2[i];
      float e = __expf(2.0f * z);
      float c = 1.0f - 2.0f / (e + 1.0f);      // tanh(z)
      float hn = (1.0f - u) * hq[i] + u * c;
      hq[i] = hn;
      tq[w][(rr0 + i) * 20 + cc] = (h16)hn;
      if (s == T_SEQ) out[(size_t)(bg * 16 + rr0 + i) * NH + cg * 16 + cc] = hn;
    }

    // ---- transpose -> one tagged 8B store; then next-x prefetch ----
    H4 pv; pv.v = *(const h16x4*)&tq[w][(l & 15) * 20 + (l >> 4) * 4];
    u64 word = (pv.q & ~TAGM) | tagpat(((unsigned)s >> 1) & 15u);
    u64* outp = hfrag + ((size_t)(s & 1) * 4 + bg) * 4096;
    cstore64(outp + dstw, word);

    if (s < T_SEQ) {
      xq0 = *(const u64*)(xb0 + (size_t)s * 393216);
      xq1 = *(const u64*)(xb1 + (size_t)s * 393216);
      xq2 = *(const u64*)(xb2 + (size_t)s * 393216);
    }
  }
}

// ============================================================
extern "C" void kernel_launch(void* const* d_in, const int* in_sizes, int n_in,
                              void* d_out, int out_size, void* d_ws, size_t ws_size,
                              hipStream_t stream) {
  const float* inp  = (const float*)d_in[0];
  const float* Win  = (const float*)d_in[1];
  const float* Whid = (const float*)d_in[2];
  const float* bstk = (const float*)d_in[3];
  const float* hid0 = (const float*)d_in[4];
  float* out = (float*)d_out;

  char* ws = (char*)d_ws;
  const size_t xBytes = (size_t)T_SEQ * NB * N3H * sizeof(h16);   // 201,326,592
  const size_t hBytes = (size_t)2 * 4 * 4096 * sizeof(u64);       //     262,144
  if (ws_size < xBytes + hBytes) return;

  h16* x = (h16*)ws;
  u64* hfrag = (u64*)(ws + xBytes);

  gru_init_h<<<dim3(16384 / 256), dim3(256), 0, stream>>>(hid0, hfrag);

  dim3 g1(32768 / P1_BM, N3H / 128);
  gru_xgemm<<<g1, dim3(256), 0, stream>>>(inp, Win, bstk, x);

  gru_steps<<<dim3(64), dim3(256), 0, stream>>>(Whid, x, hfrag, hid0, out);
}

// Round 15
// 2326.588 us; speedup vs baseline: 1.2066x; 1.0433x over previous
//
#include <hip/hip_runtime.h>
#include <hip/hip_fp16.h>
#include <math.h>

typedef _Float16 h16;
typedef __attribute__((ext_vector_type(4))) _Float16 h16x4;
typedef __attribute__((ext_vector_type(8))) _Float16 h16x8;
typedef __attribute__((ext_vector_type(4))) float f32x4;
typedef __attribute__((ext_vector_type(4))) unsigned u32x4;
typedef unsigned long long u64;

#define T_SEQ 512
#define NB    64
#define NI    512
#define NH    1024
#define N3H   3072

#define TAGM 0x0001000100010001ULL   // f16 mantissa LSBs of the 4 packed h

// Agent-scope (LLC-coherent) helpers. Relaxed per-access coherence only —
// no cache-wide fences (r2), no L2 relay (r8). h words are SELF-VALIDATING
// via 4-bit epoch in the f16 LSBs (r11 protocol, kept bit-identical).
__device__ __forceinline__ void cstore64(u64* p, u64 v) {
  __hip_atomic_store(p, v, __ATOMIC_RELAXED, __HIP_MEMORY_SCOPE_AGENT);
}
__device__ __forceinline__ u32x4 cload128(const u64* p) {
  u32x4 v;
  asm volatile("global_load_dwordx4 %0, %1, off sc0 sc1" : "=v"(v) : "v"(p));
  return v;
}
#define VMWAIT(N) do { \
  asm volatile("s_waitcnt vmcnt(" #N ")" ::: "memory"); \
  __builtin_amdgcn_sched_barrier(0); \
} while (0)

union H4 { u64 q; h16x4 v; };
union F16B { u32x4 d; u64 q[2]; h16x8 v; };

__device__ __forceinline__ u64 tagpat(unsigned e) {   // spread 4-bit epoch
  return (u64)(e & 1) | ((u64)((e >> 1) & 1) << 16)
       | ((u64)((e >> 2) & 1) << 32) | ((u64)((e >> 3) & 1) << 48);
}

// h planes: [2 parity][4 bg][4096 u64] raw f16 MFMA-fragment order:
// word 2*(kt*64+l)+q holds h[row=l&15][k = kt*32+(l>>4)*8+q*4 .. +3],
// LSB of each f16 = epoch bit. Epoch = (producing_step>>1)&15.

// ============================================================
// Kernel 0: init h^(0) parity-0 planes (raw f16 frag order, epoch 0).
// ============================================================
__global__ void gru_init_h(const float* __restrict__ hid0,
                           u64* __restrict__ hfrag) {
  int W = blockIdx.x * blockDim.x + threadIdx.x;   // 0..16383 (4 bg x 4096)
  if (W >= 16384) return;
  int bg = W >> 12;
  int w  = W & 4095;
  int kt = w >> 7;
  int lp = (w >> 1) & 63;
  int q  = w & 1;
  int cb = kt * 32 + (lp >> 4) * 8 + q * 4;
  H4 o;
  #pragma unroll
  for (int j = 0; j < 4; ++j) o.v[j] = (h16)hid0[cb + j];  // row-independent
  hfrag[(size_t)bg * 4096 + w] = o.q & ~TAGM;              // epoch tag 0
}

// ============================================================
// Kernel 1: x = inp @ W_in + b  (f16 out, CONSUMER-TRANSPOSED layout)
// x layout: [t][gate][cg][bg][cc*16 + rr]  (512B block per (t,g,cg,bg))
// r15: 2-term split-f16 (ah*bh + al*bh; residual A*bl ~3e-4 RMS, below
// the f16 x-storage rounding). sBl staging deleted -> 48 KiB LDS.
// ============================================================
#define P1_BM 128
#define P1_BK 32

__device__ __forceinline__ int p1swz(int r, int k) {
  return r * P1_BK + ((((k >> 3) ^ (r & 3)) << 3) | (k & 7));
}

__global__ __launch_bounds__(256, 2) void gru_xgemm(
    const float* __restrict__ inp, const float* __restrict__ Win,
    const float* __restrict__ bstk, h16* __restrict__ x) {
  __shared__ h16 sAh[2][P1_BM * P1_BK];
  __shared__ h16 sAl[2][P1_BM * P1_BK];
  __shared__ h16 sBh[2][P1_BM * P1_BK];   // 48 KiB total

  const int tid = threadIdx.x;
  const int l = tid & 63;
  const int w = tid >> 6;
  const int wm = (w >> 1) * 64, wn = (w & 1) * 64;
  const int mi = blockIdx.x, ni = blockIdx.y;

  const int sr  = tid >> 1;
  const int skh = (tid & 1) * 16;

  const float* aSrcBase = inp + (size_t)(sr & 63) * (T_SEQ * NI)
                              + (size_t)(mi * 2 + (sr >> 6)) * NI + skh;
  const float* bSrcBase = Win + (size_t)skh * N3H + ni * 128 + sr;

  f32x4 acc[4][4] = {};
  float aReg[16];
  float bReg[16];

  auto stage_load = [&](int ks) {
    const float* ap = aSrcBase + ks * P1_BK;
    #pragma unroll
    for (int jg = 0; jg < 4; ++jg) {
      f32x4 v = *(const f32x4*)(ap + jg * 4);
      aReg[jg*4+0] = v[0]; aReg[jg*4+1] = v[1];
      aReg[jg*4+2] = v[2]; aReg[jg*4+3] = v[3];
    }
    const float* bp = bSrcBase + (size_t)ks * P1_BK * N3H;
    #pragma unroll
    for (int j = 0; j < 16; ++j) bReg[j] = bp[(size_t)j * N3H];
  };

  auto stage_write = [&](int buf) {
    #pragma unroll
    for (int jg = 0; jg < 4; ++jg) {
      int idx = p1swz(sr, skh + jg * 4);
      h16x4 hi, lo;
      #pragma unroll
      for (int j = 0; j < 4; ++j) {
        float v = aReg[jg*4+j];
        h16 h = (h16)v; hi[j] = h; lo[j] = (h16)(v - (float)h);
      }
      *(h16x4*)&sAh[buf][idx] = hi;
      *(h16x4*)&sAl[buf][idx] = lo;
      #pragma unroll
      for (int j = 0; j < 4; ++j) hi[j] = (h16)bReg[jg*4+j];
      *(h16x4*)&sBh[buf][idx] = hi;
    }
  };

  auto compute = [&](int buf) {
    const int k0 = (l >> 4) * 8;
    h16x8 bh[4];
    #pragma unroll
    for (int nt = 0; nt < 4; ++nt) {
      int idx = p1swz(wn + nt * 16 + (l & 15), k0);
      bh[nt] = *(const h16x8*)&sBh[buf][idx];
    }
    #pragma unroll
    for (int mt = 0; mt < 4; ++mt) {
      int idx = p1swz(wm + mt * 16 + (l & 15), k0);
      h16x8 ah = *(const h16x8*)&sAh[buf][idx];
      h16x8 al = *(const h16x8*)&sAl[buf][idx];
      #pragma unroll
      for (int nt = 0; nt < 4; ++nt) {
        acc[mt][nt] = __builtin_amdgcn_mfma_f32_16x16x32_f16(ah, bh[nt], acc[mt][nt], 0, 0, 0);
        acc[mt][nt] = __builtin_amdgcn_mfma_f32_16x16x32_f16(al, bh[nt], acc[mt][nt], 0, 0, 0);
      }
    }
  };

  stage_load(0);
  stage_write(0);
  __syncthreads();
  for (int ks = 0; ks < 16; ++ks) {
    int buf = ks & 1;
    if (ks < 15) stage_load(ks + 1);
    compute(buf);
    if (ks < 15) stage_write(buf ^ 1);
    __syncthreads();
  }

  const int t = mi * 2 + (wm >> 6);
  const int rrb = (l >> 4) * 4;
  #pragma unroll
  for (int nt = 0; nt < 4; ++nt) {
    int colhi = ni * 8 + (wn >> 4) + nt;
    int gg  = colhi >> 6;
    int cgx = colhi & 63;
    float bias = bstk[(colhi << 4) + (l & 15)];
    #pragma unroll
    for (int mt = 0; mt < 4; ++mt) {
      h16x4 v;
      #pragma unroll
      for (int i = 0; i < 4; ++i) v[i] = (h16)(acc[mt][nt][i] + bias);
      size_t idx = ((((size_t)t * 3 + gg) * 64 + cgx) * 4 + mt) * 256
                 + (size_t)(l & 15) * 16 + rrb;
      *(h16x4*)&x[idx] = v;
    }
  }
}

// ============================================================
// Kernel 2: persistent GRU recurrence — 64 WGs x 4 waves (r13 verbatim,
// the proven 2.03 ms configuration; r14's ring-8 was VGPR-infeasible).
// ============================================================
__global__ __launch_bounds__(256, 1) void gru_steps(
    const float* __restrict__ Whid,   // [1024][3072] f32
    const h16* __restrict__ x,        // transposed layout, f16
    u64* __restrict__ hfrag,          // [2 par][4 bg][4096] u64 tagged frags
    const float* __restrict__ hid0,   // [1024]
    float* __restrict__ out) {        // [64][1024] f32
  __shared__ h16 Albuf[2][16384];     // 64 KiB: staged h plane, parity dbuf
  __shared__ h16 Bc2[4 * 8 * 64 * 8]; // 32 KiB: gate-c B frags kt=24..31
  __shared__ h16 tq[4][16 * 20];      // per-wave store-transpose staging

  const int tid = threadIdx.x;
  const int l = tid & 63;
  const int w = tid >> 6;              // wave id 0..3
  const int cg = (blockIdx.x >> 2) * 4 + w;   // this wave's 16-col tile
  const int bg = blockIdx.x & 3;

  // ---- prologue: B fragments -> registers (+ gate-c tail -> LDS) ----
  h16x8 Br[32], Bu[32], Bc[24];
  {
    const float* b0 = Whid + (size_t)cg * 16 + (l & 15);
    #pragma unroll
    for (int kt = 0; kt < 32; ++kt) {
      const float* src = b0 + (size_t)(kt * 32 + (l >> 4) * 8) * N3H;
      h16x8 v;
      #pragma unroll
      for (int j = 0; j < 8; ++j) v[j] = (h16)src[(size_t)j * N3H];
      Br[kt] = v;
    }
    const float* b1 = b0 + NH;
    #pragma unroll
    for (int kt = 0; kt < 32; ++kt) {
      const float* src = b1 + (size_t)(kt * 32 + (l >> 4) * 8) * N3H;
      h16x8 v;
      #pragma unroll
      for (int j = 0; j < 8; ++j) v[j] = (h16)src[(size_t)j * N3H];
      Bu[kt] = v;
    }
    const float* b2 = b0 + 2 * NH;
    #pragma unroll
    for (int kt = 0; kt < 24; ++kt) {
      const float* src = b2 + (size_t)(kt * 32 + (l >> 4) * 8) * N3H;
      h16x8 v;
      #pragma unroll
      for (int j = 0; j < 8; ++j) v[j] = (h16)src[(size_t)j * N3H];
      Bc[kt] = v;
    }
    #pragma unroll
    for (int kt = 24; kt < 32; ++kt) {
      const float* src = b2 + (size_t)(kt * 32 + (l >> 4) * 8) * N3H;
      h16x8 v;
      #pragma unroll
      for (int j = 0; j < 8; ++j) v[j] = (h16)src[(size_t)j * N3H];
      *(h16x8*)&Bc2[(size_t)((w * 8 + (kt - 24)) * 64 + l) * 8] = v;
    }
  }

  const int rr0 = (l >> 4) * 4, cc = l & 15;

  float hq[4];
  {
    float h0 = hid0[cg * 16 + cc];
    #pragma unroll
    for (int i = 0; i < 4; ++i) hq[i] = h0;
  }

  const char* xb0 = (const char*)(x + ((((size_t)0 * 64 + cg) * 4 + bg) * 256)
                                    + (size_t)cc * 16 + rr0);
  const char* xb1 = xb0 + 64 * 4 * 256 * 2;
  const char* xb2 = xb1 + 64 * 4 * 256 * 2;
  u64 xq0 = *(const u64*)xb0, xq1 = *(const u64*)xb1, xq2 = *(const u64*)xb2;

  const int dstw = cg * 64 + ((l >> 4) >> 1) * 32 + (l & 15) * 2 + ((l >> 4) & 1);

  VMWAIT(0);           // deterministic vm state entering the loop
  __syncthreads();

  for (int s = 1; s <= T_SEQ; ++s) {
    const int par = (s - 1) & 1;
    const u64* plane = hfrag + ((size_t)par * 4 + bg) * 4096;
    const u64 patc = tagpat((((unsigned)(s - 1)) >> 1) & 15u);

    // ---- cooperative pull: 8 frags/thread (2 chunks of 4), 2MB/step/chip ----
    F16B W0[4], W1[4];
    #pragma unroll
    for (int j = 0; j < 4; ++j)
      W0[j].d = cload128(plane + (size_t)(j * 256 + tid) * 2);
    #pragma unroll
    for (int j = 0; j < 4; ++j)
      W1[j].d = cload128(plane + (size_t)((4 + j) * 256 + tid) * 2);

    VMWAIT(4);          // strays (<=4: store+3 x-loads) + chunk0 retired
    for (int tries = 0; tries < 30000; ++tries) {
      unsigned bad = 0;
      #pragma unroll
      for (int j = 0; j < 4; ++j)
        bad |= ((((W0[j].q[0] ^ patc) | (W0[j].q[1] ^ patc)) & TAGM) != 0ULL)
                 ? (1u << j) : 0u;
      if (bad == 0) break;
      if (tries > 4) __builtin_amdgcn_s_sleep(1);
      #pragma unroll
      for (int j = 0; j < 4; ++j)
        if (bad & (1u << j))
          W0[j].d = cload128(plane + (size_t)(j * 256 + tid) * 2);
      VMWAIT(0);
    }
    #pragma unroll
    for (int j = 0; j < 4; ++j)
      *(h16x8*)&Albuf[par][(size_t)(j * 256 + tid) * 8] = W0[j].v;

    VMWAIT(0);          // chunk1 retired
    for (int tries = 0; tries < 30000; ++tries) {
      unsigned bad = 0;
      #pragma unroll
      for (int j = 0; j < 4; ++j)
        bad |= ((((W1[j].q[0] ^ patc) | (W1[j].q[1] ^ patc)) & TAGM) != 0ULL)
                 ? (1u << j) : 0u;
      if (bad == 0) break;
      if (tries > 4) __builtin_amdgcn_s_sleep(1);
      #pragma unroll
      for (int j = 0; j < 4; ++j)
        if (bad & (1u << j))
          W1[j].d = cload128(plane + (size_t)((4 + j) * 256 + tid) * 2);
      VMWAIT(0);
    }
    #pragma unroll
    for (int j = 0; j < 4; ++j)
      *(h16x8*)&Albuf[par][(size_t)((4 + j) * 256 + tid) * 8] = W1[j].v;

    __syncthreads();    // plane staged; safe vs parity dbuf (2-plane rotation)

    // ---- 96 MFMA per wave: A from LDS (broadcast), B from VGPR/LDS ----
    f32x4 ac0 = {}, ac1 = {}, ac2 = {};
    #pragma unroll
    for (int kt = 0; kt < 32; ++kt) {
      h16x8 a = *(const h16x8*)&Albuf[par][(size_t)(kt * 64 + l) * 8];
      ac0 = __builtin_amdgcn_mfma_f32_16x16x32_f16(a, Br[kt], ac0, 0, 0, 0);
      ac1 = __builtin_amdgcn_mfma_f32_16x16x32_f16(a, Bu[kt], ac1, 0, 0, 0);
      h16x8 bc = (kt < 24)
          ? Bc[kt]
          : *(const h16x8*)&Bc2[(size_t)((w * 8 + (kt - 24)) * 64 + l) * 8];
      ac2 = __builtin_amdgcn_mfma_f32_16x16x32_f16(a, bc, ac2, 0, 0, 0);
    }

    // ---- gates fully in-register ----
    H4 xr; xr.q = xq0;
    H4 xu; xu.q = xq1;
    H4 xc; xc.q = xq2;
    #pragma unroll
    for (int i = 0; i < 4; ++i) {
      float r = 1.0f / (1.0f + __expf(-((float)xr.v[i] + ac0[i])));
      float u = 1.0f / (1.0f + __expf(-((float)xu.v[i] + ac1[i])));
      float z = (float)xc.v[i] + r * ac2[i];
      float e = __expf(2.0f * z);
      float c = 1.0f - 2.0f / (e + 1.0f);      // tanh(z)
      float hn = (1.0f - u) * hq[i] + u * c;
      hq[i] = hn;
      tq[w][(rr0 + i) * 20 + cc] = (h16)hn;
      if (s == T_SEQ) out[(size_t)(bg * 16 + rr0 + i) * NH + cg * 16 + cc] = hn;
    }

    // ---- transpose -> one tagged 8B store; then next-x prefetch ----
    H4 pv; pv.v = *(const h16x4*)&tq[w][(l & 15) * 20 + (l >> 4) * 4];
    u64 word = (pv.q & ~TAGM) | tagpat(((unsigned)s >> 1) & 15u);
    u64* outp = hfrag + ((size_t)(s & 1) * 4 + bg) * 4096;
    cstore64(outp + dstw, word);

    if (s < T_SEQ) {
      xq0 = *(const u64*)(xb0 + (size_t)s * 393216);
      xq1 = *(const u64*)(xb1 + (size_t)s * 393216);
      xq2 = *(const u64*)(xb2 + (size_t)s * 393216);
    }
  }
}

// ============================================================
extern "C" void kernel_launch(void* const* d_in, const int* in_sizes, int n_in,
                              void* d_out, int out_size, void* d_ws, size_t ws_size,
                              hipStream_t stream) {
  const float* inp  = (const float*)d_in[0];
  const float* Win  = (const float*)d_in[1];
  const float* Whid = (const float*)d_in[2];
  const float* bstk = (const float*)d_in[3];
  const float* hid0 = (const float*)d_in[4];
  float* out = (float*)d_out;

  char* ws = (char*)d_ws;
  const size_t xBytes = (size_t)T_SEQ * NB * N3H * sizeof(h16);   // 201,326,592
  const size_t hBytes = (size_t)2 * 4 * 4096 * sizeof(u64);       //     262,144
  if (ws_size < xBytes + hBytes) return;

  h16* x = (h16*)ws;
  u64* hfrag = (u64*)(ws + xBytes);

  gru_init_h<<<dim3(16384 / 256), dim3(256), 0, stream>>>(hid0, hfrag);

  dim3 g1(32768 / P1_BM, N3H / 128);
  gru_xgemm<<<g1, dim3(256), 0, stream>>>(inp, Win, bstk, x);

  gru_steps<<<dim3(64), dim3(256), 0, stream>>>(Whid, x, hfrag, hid0, out);
}